// Round 2
// baseline (8142.057 us; speedup 1.0000x reference)
//
#include <hip/hip_runtime.h>

typedef unsigned short u16;
typedef unsigned int   u32;
typedef _Float16 f16;
typedef _Float16 half2v __attribute__((ext_vector_type(2)));
typedef _Float16 half8v __attribute__((ext_vector_type(8)));
typedef float float4v __attribute__((ext_vector_type(4)));

#define B_  256
#define T_  512
#define I_  64
#define H_  256
#define G_  1024   // 4*H
#define BT_ (B_*T_)

static __device__ __forceinline__ float fdot2u(u32 a, u32 b, float c) {
#if defined(__has_builtin) && __has_builtin(__builtin_amdgcn_fdot2)
  return __builtin_amdgcn_fdot2(__builtin_bit_cast(half2v, a),
                                __builtin_bit_cast(half2v, b), c, false);
#else
  half2v av = __builtin_bit_cast(half2v, a), bv = __builtin_bit_cast(half2v, b);
  return c + (float)av.x * (float)bv.x + (float)av.y * (float)bv.y;
#endif
}

static __device__ __forceinline__ float sig_(float x) {
  return 1.0f / (1.0f + __expf(-x));
}
static __device__ __forceinline__ float tanh_(float x) {
  float ax = fminf(fabsf(x), 15.0f);
  float e  = __expf(2.0f * ax);
  float t  = (e - 1.0f) / (e + 1.0f);
  return copysignf(t, x);
}

// ---------------- small prep kernels ----------------

__global__ void cvt_f16(const float* __restrict__ in, u16* __restrict__ out, int n) {
  int i = blockIdx.x * blockDim.x + threadIdx.x;
  if (i < n) out[i] = __builtin_bit_cast(u16, (f16)in[i]);
}

__global__ void split_w(const float* __restrict__ w, u16* __restrict__ hi,
                        u16* __restrict__ lo, int n) {
  int i = blockIdx.x * blockDim.x + threadIdx.x;
  if (i < n) {
    float v = w[i];
    f16 h = (f16)v;
    float r = v - (float)h;
    hi[i] = __builtin_bit_cast(u16, h);
    lo[i] = __builtin_bit_cast(u16, (f16)r);
  }
}

__global__ void bias_sum(const float* __restrict__ a, const float* __restrict__ b,
                         float* __restrict__ o, int n) {
  int i = blockIdx.x * blockDim.x + threadIdx.x;
  if (i < n) o[i] = a[i] + b[i];
}

// ---------------- f16 MFMA GEMM with weight hi/lo split ----------------
// C[m][n] = sum_k A[m][k] * (Bh[n][k] + Bl[n][k]) + bias[n]
// A rows remapped: chunk-local row m -> global row (m>>tcl)*T_ + t0 + (m & (Tc-1))
template<int BN>
__global__ __launch_bounds__(256) void gemm_ws(
    const u16* __restrict__ A, const u16* __restrict__ Bh, const u16* __restrict__ Bl,
    const float* __restrict__ bias, float* __restrict__ C,
    int K, int tcl, int t0, int N)
{
  constexpr int BM = 128, BK = 64, LDT = 72;  // LDT in f16 units (144 B rows, 16B aligned)
  __shared__ u16 As[BM * LDT];
  __shared__ u16 Bhs[BN * LDT];
  __shared__ u16 Bls[BN * LDT];
  const int tid = threadIdx.x, wave = tid >> 6, lane = tid & 63;
  const int m0 = blockIdx.x * BM, n0 = blockIdx.y * BN;
  constexpr int WNT = BN / 32;          // n-tiles per wave
  const int wm0 = (wave >> 1) * 64, wn0 = (wave & 1) * (BN / 2);
  const int tcmask = (1 << tcl) - 1;
  float4v acc[4][WNT];
  for (int i = 0; i < 4; i++)
    for (int j = 0; j < WNT; j++) acc[i][j] = (float4v){0.f, 0.f, 0.f, 0.f};
  const int lrow = lane & 15, lk = (lane >> 4) * 8;

  for (int k0 = 0; k0 < K; k0 += BK) {
    __syncthreads();
#pragma unroll
    for (int i = 0; i < 4; i++) {
      int idx = tid + i * 256, row = idx >> 3, u = idx & 7;
      int m = m0 + row;
      int rg = (m >> tcl) * T_ + t0 + (m & tcmask);
      *(uint4*)(As + row * LDT + u * 8) =
          *(const uint4*)(A + (size_t)rg * K + k0 + u * 8);
    }
#pragma unroll
    for (int i = 0; i < WNT; i++) {
      int idx = tid + i * 256, row = idx >> 3, u = idx & 7;
      size_t go = (size_t)(n0 + row) * K + k0 + u * 8;
      *(uint4*)(Bhs + row * LDT + u * 8) = *(const uint4*)(Bh + go);
      *(uint4*)(Bls + row * LDT + u * 8) = *(const uint4*)(Bl + go);
    }
    __syncthreads();
#pragma unroll
    for (int ks = 0; ks < 2; ++ks) {
      int col = ks * 32 + lk;
      half8v af[4];
#pragma unroll
      for (int mt = 0; mt < 4; mt++)
        af[mt] = *(const half8v*)(const void*)(As + (wm0 + mt * 16 + lrow) * LDT + col);
#pragma unroll
      for (int nt = 0; nt < WNT; nt++) {
        half8v bhv = *(const half8v*)(const void*)(Bhs + (wn0 + nt * 16 + lrow) * LDT + col);
        half8v blv = *(const half8v*)(const void*)(Bls + (wn0 + nt * 16 + lrow) * LDT + col);
#pragma unroll
        for (int mt = 0; mt < 4; mt++) {
          acc[mt][nt] = __builtin_amdgcn_mfma_f32_16x16x32_f16(af[mt], bhv, acc[mt][nt], 0, 0, 0);
          acc[mt][nt] = __builtin_amdgcn_mfma_f32_16x16x32_f16(af[mt], blv, acc[mt][nt], 0, 0, 0);
        }
      }
    }
  }
  const int crow = (lane >> 4) * 4, ccol = lane & 15;
#pragma unroll
  for (int nt = 0; nt < WNT; nt++) {
    int n = n0 + wn0 + nt * 16 + ccol;
    float bv = bias[n];
#pragma unroll
    for (int mt = 0; mt < 4; mt++) {
#pragma unroll
      for (int r = 0; r < 4; r++) {
        int m = m0 + wm0 + mt * 16 + crow + r;
        C[(size_t)m * N + n] = acc[mt][nt][r] + bv;
      }
    }
  }
}

// ---------------- persistent per-batch LSTM scan ----------------
// One block per batch element, 256 threads (4 waves, 1 wave/SIMD -> VGPR cap 512).
// Thread tid owns the 4 gate rows of hidden unit tid (rows g*256+tid, g=i,f,g,o):
//   cols [0,192) in registers (384 VGPRs), cols [192,256) in LDS (128 KB).
// h double-buffered in LDS -> ONE barrier per step. c stays in a register.
// LDS tail layout: block (g,q) holds uint4 chunk q of gate g for all 256 tids,
// at ((g*8+q)*256 + tid)*16 B -> lane i reads base+16*i (contiguous b128, fast path).
__global__ __launch_bounds__(256, 1) void lstm_scan(
    const u16* __restrict__ whh, const float* __restrict__ xp,
    u16* __restrict__ hout, float* __restrict__ cst, u16* __restrict__ hst,
    int Tc, int t0)
{
  __shared__ u16 wt[32 * 256 * 8];   // 128 KB tail
  __shared__ u32 hbuf[2][128];       // h as 256 packed f16, double buffered
  const int tid = threadIdx.x, b = blockIdx.x;

  uint4 w[4][24];
#pragma unroll
  for (int g = 0; g < 4; g++) {
    const uint4* gp = (const uint4*)(whh + (size_t)(g * 256 + tid) * 256);
#pragma unroll
    for (int i = 0; i < 24; i++) w[g][i] = gp[i];
#pragma unroll
    for (int q = 0; q < 8; q++)
      *(uint4*)(wt + ((size_t)(g * 8 + q) * 256 + tid) * 8) = gp[24 + q];
  }

  float cc = 0.f;
  if (t0 == 0) {
    if (tid < 128) hbuf[0][tid] = 0u;
  } else {
    cc = cst[(size_t)b * 256 + tid];
    if (tid < 128) hbuf[0][tid] = ((const u32*)hst)[(size_t)b * 128 + tid];
  }
  __syncthreads();

  const float* xpb = xp + (size_t)b * Tc * 1024;
  float xn[4];
#pragma unroll
  for (int g = 0; g < 4; g++) xn[g] = xpb[g * 256 + tid];
  u16* houtb = hout + ((size_t)b * T_ + t0) * 256;

  u16 hb = 0;
  for (int tt = 0; tt < Tc; ++tt) {
    float a0 = xn[0], a1 = xn[1], a2 = xn[2], a3 = xn[3];
    if (tt + 1 < Tc) {
#pragma unroll
      for (int g = 0; g < 4; g++)
        xn[g] = xpb[(size_t)(tt + 1) * 1024 + g * 256 + tid];
    }
    const uint4* hq = (const uint4*)hbuf[tt & 1];
#pragma unroll
    for (int kc = 0; kc < 24; ++kc) {
      uint4 hv = hq[kc];
      a0 = fdot2u(w[0][kc].x, hv.x, a0); a0 = fdot2u(w[0][kc].y, hv.y, a0);
      a0 = fdot2u(w[0][kc].z, hv.z, a0); a0 = fdot2u(w[0][kc].w, hv.w, a0);
      a1 = fdot2u(w[1][kc].x, hv.x, a1); a1 = fdot2u(w[1][kc].y, hv.y, a1);
      a1 = fdot2u(w[1][kc].z, hv.z, a1); a1 = fdot2u(w[1][kc].w, hv.w, a1);
      a2 = fdot2u(w[2][kc].x, hv.x, a2); a2 = fdot2u(w[2][kc].y, hv.y, a2);
      a2 = fdot2u(w[2][kc].z, hv.z, a2); a2 = fdot2u(w[2][kc].w, hv.w, a2);
      a3 = fdot2u(w[3][kc].x, hv.x, a3); a3 = fdot2u(w[3][kc].y, hv.y, a3);
      a3 = fdot2u(w[3][kc].z, hv.z, a3); a3 = fdot2u(w[3][kc].w, hv.w, a3);
    }
#pragma unroll
    for (int q = 0; q < 8; ++q) {
      uint4 hv = hq[24 + q];
      uint4 w0 = *(const uint4*)(wt + ((size_t)(0 * 8 + q) * 256 + tid) * 8);
      uint4 w1 = *(const uint4*)(wt + ((size_t)(1 * 8 + q) * 256 + tid) * 8);
      uint4 w2 = *(const uint4*)(wt + ((size_t)(2 * 8 + q) * 256 + tid) * 8);
      uint4 w3 = *(const uint4*)(wt + ((size_t)(3 * 8 + q) * 256 + tid) * 8);
      a0 = fdot2u(w0.x, hv.x, a0); a0 = fdot2u(w0.y, hv.y, a0);
      a0 = fdot2u(w0.z, hv.z, a0); a0 = fdot2u(w0.w, hv.w, a0);
      a1 = fdot2u(w1.x, hv.x, a1); a1 = fdot2u(w1.y, hv.y, a1);
      a1 = fdot2u(w1.z, hv.z, a1); a1 = fdot2u(w1.w, hv.w, a1);
      a2 = fdot2u(w2.x, hv.x, a2); a2 = fdot2u(w2.y, hv.y, a2);
      a2 = fdot2u(w2.z, hv.z, a2); a2 = fdot2u(w2.w, hv.w, a2);
      a3 = fdot2u(w3.x, hv.x, a3); a3 = fdot2u(w3.y, hv.y, a3);
      a3 = fdot2u(w3.z, hv.z, a3); a3 = fdot2u(w3.w, hv.w, a3);
    }
    float iv = sig_(a0), fv = sig_(a1), gv = tanh_(a2), ov = sig_(a3);
    cc = fv * cc + iv * gv;
    float hval = ov * tanh_(cc);
    hb = __builtin_bit_cast(u16, (f16)hval);
    ((u16*)hbuf[(tt + 1) & 1])[tid] = hb;
    houtb[(size_t)tt * 256 + tid] = hb;
    __syncthreads();
  }
  cst[(size_t)b * 256 + tid] = cc;
  hst[(size_t)b * 256 + tid] = hb;
}

// ---------------- host ----------------

extern "C" void kernel_launch(void* const* d_in, const int* in_sizes, int n_in,
                              void* d_out, int out_size, void* d_ws, size_t ws_size,
                              hipStream_t stream)
{
  const float* x      = (const float*)d_in[0];
  const float* Wih[4] = {(const float*)d_in[1], (const float*)d_in[5],
                         (const float*)d_in[9], (const float*)d_in[13]};
  const float* Whh[4] = {(const float*)d_in[2], (const float*)d_in[6],
                         (const float*)d_in[10], (const float*)d_in[14]};
  const float* bi[4]  = {(const float*)d_in[3], (const float*)d_in[7],
                         (const float*)d_in[11], (const float*)d_in[15]};
  const float* bh[4]  = {(const float*)d_in[4], (const float*)d_in[8],
                         (const float*)d_in[12], (const float*)d_in[16]};
  const float* outW   = (const float*)d_in[17];
  const float* outb   = (const float*)d_in[18];

  char* ws = (char*)d_ws;
  size_t off = 0;
  auto alc = [&](size_t bytes) -> char* {
    char* p = ws + off;
    off = (off + bytes + 255) & ~(size_t)255;
    return p;
  };

  u16* xf  = (u16*)alc((size_t)BT_ * I_ * 2);
  u16* hb0 = (u16*)alc((size_t)BT_ * H_ * 2);
  u16* hb1 = (u16*)alc((size_t)BT_ * H_ * 2);
  int wihn[4] = {G_ * I_, G_ * H_, G_ * H_, G_ * H_};
  u16 *wihH[4], *wihL[4], *whhH[4];
  float* bsum[4];
  for (int l = 0; l < 4; l++) {
    wihH[l] = (u16*)alc((size_t)wihn[l] * 2);
    wihL[l] = (u16*)alc((size_t)wihn[l] * 2);
    whhH[l] = (u16*)alc((size_t)G_ * H_ * 2);
    bsum[l] = (float*)alc((size_t)G_ * 4);
  }
  u16* owH = (u16*)alc((size_t)I_ * H_ * 2);
  u16* owL = (u16*)alc((size_t)I_ * H_ * 2);
  float* cst = (float*)alc((size_t)B_ * H_ * 4);
  u16*   hst = (u16*)alc((size_t)B_ * H_ * 2);

  int Tc = T_;
  while (Tc > 16 && off + (size_t)B_ * Tc * G_ * 4 + 4096 > ws_size) Tc >>= 1;
  float* xpb = (float*)alc((size_t)B_ * Tc * G_ * 4);
  int tcl = 0;
  while ((1 << tcl) < Tc) tcl++;

  {
    int n = BT_ * I_;
    cvt_f16<<<dim3((n + 255) / 256), dim3(256), 0, stream>>>(x, xf, n);
  }
  for (int l = 0; l < 4; l++) {
    split_w<<<dim3((wihn[l] + 255) / 256), dim3(256), 0, stream>>>(Wih[l], wihH[l], wihL[l], wihn[l]);
    cvt_f16<<<dim3((G_ * H_ + 255) / 256), dim3(256), 0, stream>>>(Whh[l], whhH[l], G_ * H_);
    bias_sum<<<dim3(4), dim3(256), 0, stream>>>(bi[l], bh[l], bsum[l], G_);
  }
  split_w<<<dim3((I_ * H_ + 255) / 256), dim3(256), 0, stream>>>(outW, owH, owL, I_ * H_);

  for (int l = 0; l < 4; l++) {
    const u16* Ain = (l == 0) ? xf : ((l == 1) ? hb0 : (l == 2) ? hb1 : hb0);
    u16* Hout = (l & 1) ? hb1 : hb0;
    int K = (l == 0) ? I_ : H_;
    for (int t0 = 0; t0 < T_; t0 += Tc) {
      gemm_ws<128><<<dim3((B_ * Tc) / 128, G_ / 128), dim3(256), 0, stream>>>(
          Ain, wihH[l], wihL[l], bsum[l], xpb, K, tcl, t0, G_);
      lstm_scan<<<dim3(B_), dim3(256), 0, stream>>>(whhH[l], xpb, Hout, cst, hst, Tc, t0);
    }
  }

  gemm_ws<64><<<dim3(BT_ / 128, 1), dim3(256), 0, stream>>>(
      hb1, owH, owL, outb, (float*)d_out, H_, 9, 0, I_);
}

// Round 3
// 5278.707 us; speedup vs baseline: 1.5424x; 1.5424x over previous
//
#include <hip/hip_runtime.h>

typedef unsigned short u16;
typedef unsigned int   u32;
typedef _Float16 f16;
typedef _Float16 half2v __attribute__((ext_vector_type(2)));
typedef _Float16 half8v __attribute__((ext_vector_type(8)));
typedef float float4v __attribute__((ext_vector_type(4)));

#define B_  256
#define T_  512
#define I_  64
#define H_  256
#define G_  1024   // 4*H
#define BT_ (B_*T_)

static __device__ __forceinline__ float fdot2u(u32 a, u32 b, float c) {
#if defined(__has_builtin) && __has_builtin(__builtin_amdgcn_fdot2)
  return __builtin_amdgcn_fdot2(__builtin_bit_cast(half2v, a),
                                __builtin_bit_cast(half2v, b), c, false);
#else
  half2v av = __builtin_bit_cast(half2v, a), bv = __builtin_bit_cast(half2v, b);
  return c + (float)av.x * (float)bv.x + (float)av.y * (float)bv.y;
#endif
}

static __device__ __forceinline__ float sig_(float x) {
  return 1.0f / (1.0f + __expf(-x));
}
static __device__ __forceinline__ float tanh_(float x) {
  float ax = fminf(fabsf(x), 15.0f);
  float e  = __expf(2.0f * ax);
  float t  = (e - 1.0f) / (e + 1.0f);
  return copysignf(t, x);
}

// ---------------- small prep kernels ----------------

__global__ void cvt_f16(const float* __restrict__ in, u16* __restrict__ out, int n) {
  int i = blockIdx.x * blockDim.x + threadIdx.x;
  if (i < n) out[i] = __builtin_bit_cast(u16, (f16)in[i]);
}

__global__ void split_w(const float* __restrict__ w, u16* __restrict__ hi,
                        u16* __restrict__ lo, int n) {
  int i = blockIdx.x * blockDim.x + threadIdx.x;
  if (i < n) {
    float v = w[i];
    f16 h = (f16)v;
    float r = v - (float)h;
    hi[i] = __builtin_bit_cast(u16, h);
    lo[i] = __builtin_bit_cast(u16, (f16)r);
  }
}

__global__ void bias_sum(const float* __restrict__ a, const float* __restrict__ b,
                         float* __restrict__ o, int n) {
  int i = blockIdx.x * blockDim.x + threadIdx.x;
  if (i < n) o[i] = a[i] + b[i];
}

// ---------------- f16 MFMA GEMM with weight hi/lo split ----------------
// C[m][n] = sum_k A[m][k] * (Bh[n][k] + Bl[n][k]) + bias[n]
// A rows remapped: chunk-local row m -> global row (m>>tcl)*T_ + t0 + (m & (Tc-1))
template<int BN>
__global__ __launch_bounds__(256) void gemm_ws(
    const u16* __restrict__ A, const u16* __restrict__ Bh, const u16* __restrict__ Bl,
    const float* __restrict__ bias, float* __restrict__ C,
    int K, int tcl, int t0, int N)
{
  constexpr int BM = 128, BK = 64, LDT = 72;  // LDT in f16 units (144 B rows, 16B aligned)
  __shared__ u16 As[BM * LDT];
  __shared__ u16 Bhs[BN * LDT];
  __shared__ u16 Bls[BN * LDT];
  const int tid = threadIdx.x, wave = tid >> 6, lane = tid & 63;
  const int m0 = blockIdx.x * BM, n0 = blockIdx.y * BN;
  constexpr int WNT = BN / 32;          // n-tiles per wave
  const int wm0 = (wave >> 1) * 64, wn0 = (wave & 1) * (BN / 2);
  const int tcmask = (1 << tcl) - 1;
  float4v acc[4][WNT];
  for (int i = 0; i < 4; i++)
    for (int j = 0; j < WNT; j++) acc[i][j] = (float4v){0.f, 0.f, 0.f, 0.f};
  const int lrow = lane & 15, lk = (lane >> 4) * 8;

  for (int k0 = 0; k0 < K; k0 += BK) {
    __syncthreads();
#pragma unroll
    for (int i = 0; i < 4; i++) {
      int idx = tid + i * 256, row = idx >> 3, u = idx & 7;
      int m = m0 + row;
      int rg = (m >> tcl) * T_ + t0 + (m & tcmask);
      *(uint4*)(As + row * LDT + u * 8) =
          *(const uint4*)(A + (size_t)rg * K + k0 + u * 8);
    }
#pragma unroll
    for (int i = 0; i < WNT; i++) {
      int idx = tid + i * 256, row = idx >> 3, u = idx & 7;
      size_t go = (size_t)(n0 + row) * K + k0 + u * 8;
      *(uint4*)(Bhs + row * LDT + u * 8) = *(const uint4*)(Bh + go);
      *(uint4*)(Bls + row * LDT + u * 8) = *(const uint4*)(Bl + go);
    }
    __syncthreads();
#pragma unroll
    for (int ks = 0; ks < 2; ++ks) {
      int col = ks * 32 + lk;
      half8v af[4];
#pragma unroll
      for (int mt = 0; mt < 4; mt++)
        af[mt] = *(const half8v*)(const void*)(As + (wm0 + mt * 16 + lrow) * LDT + col);
#pragma unroll
      for (int nt = 0; nt < WNT; nt++) {
        half8v bhv = *(const half8v*)(const void*)(Bhs + (wn0 + nt * 16 + lrow) * LDT + col);
        half8v blv = *(const half8v*)(const void*)(Bls + (wn0 + nt * 16 + lrow) * LDT + col);
#pragma unroll
        for (int mt = 0; mt < 4; mt++) {
          acc[mt][nt] = __builtin_amdgcn_mfma_f32_16x16x32_f16(af[mt], bhv, acc[mt][nt], 0, 0, 0);
          acc[mt][nt] = __builtin_amdgcn_mfma_f32_16x16x32_f16(af[mt], blv, acc[mt][nt], 0, 0, 0);
        }
      }
    }
  }
  const int crow = (lane >> 4) * 4, ccol = lane & 15;
#pragma unroll
  for (int nt = 0; nt < WNT; nt++) {
    int n = n0 + wn0 + nt * 16 + ccol;
    float bv = bias[n];
#pragma unroll
    for (int mt = 0; mt < 4; mt++) {
#pragma unroll
      for (int r = 0; r < 4; r++) {
        int m = m0 + wm0 + mt * 16 + crow + r;
        C[(size_t)m * N + n] = acc[mt][nt][r] + bv;
      }
    }
  }
}

// ---------------- persistent per-batch LSTM scan ----------------
// One block per batch element, 512 threads = 8 waves, amdgpu_waves_per_eu(2,2)
// pins the RA budget at 256 VGPR/wave (min=max -> scheduler cannot target
// higher occupancy and spill; LDS 129 KB caps us at 1 block/CU anyway).
// Lane L of wave w owns hidden unit u = w*32 + (L&31); lanes L<32 own gate
// rows {i,g} of u, lanes L>=32 own {f,o}. Weight cols [0,192) live in 192
// VGPRs (48 uint4), cols [192,256) in LDS (128 KB, [chunk][row] layout so a
// wave's 32 lanes read contiguous 16B -> conflict-free b128).
// Gate exchange via __shfl_xor(32) (same wave) -> ONE barrier per step.
__global__ __launch_bounds__(512) __attribute__((amdgpu_waves_per_eu(2, 2)))
void lstm_scan(
    const u16* __restrict__ whh, const float* __restrict__ xp,
    u16* __restrict__ hout, float* __restrict__ cst, u16* __restrict__ hst,
    int Tc, int t0)
{
  __shared__ u16 wt[8 * 1024 * 8];   // 128 KB tail: chunk q of row r at (q*1024+r)*16B
  __shared__ u32 hbuf[2][128];       // h as 256 packed f16, double buffered
  const int tid = threadIdx.x, b = blockIdx.x;
  const int lane = tid & 63, wv = tid >> 6;
  const int u = wv * 32 + (lane & 31);   // hidden unit
  const int g0 = lane >> 5;              // 0 -> rows {i,g}; 1 -> rows {f,o}
  const int r0 = g0 * 256 + u;           // i or f row
  const int r1 = (g0 + 2) * 256 + u;     // g or o row

  uint4 w0[24], w1[24];
  {
    const uint4* gp0 = (const uint4*)(whh + (size_t)r0 * 256);
    const uint4* gp1 = (const uint4*)(whh + (size_t)r1 * 256);
#pragma unroll
    for (int i = 0; i < 24; i++) { w0[i] = gp0[i]; w1[i] = gp1[i]; }
#pragma unroll
    for (int q = 0; q < 8; q++) {
      *(uint4*)(wt + (size_t)(q * 1024 + r0) * 8) = gp0[24 + q];
      *(uint4*)(wt + (size_t)(q * 1024 + r1) * 8) = gp1[24 + q];
    }
  }

  float cc = 0.f;
  if (t0 == 0) {
    if (tid < 128) hbuf[0][tid] = 0u;
  } else {
    cc = cst[(size_t)b * 256 + u];
    if (tid < 128) hbuf[0][tid] = ((const u32*)hst)[(size_t)b * 128 + tid];
  }
  __syncthreads();

  const float* xpb = xp + (size_t)b * Tc * 1024;
  float xn0 = xpb[r0], xn1 = xpb[r1];
  u16* houtb = hout + ((size_t)b * T_ + t0) * 256;

  u16 hb = 0;
  for (int tt = 0; tt < Tc; ++tt) {
    float a0 = xn0, a1 = xn1;
    if (tt + 1 < Tc) {
      xn0 = xpb[(size_t)(tt + 1) * 1024 + r0];
      xn1 = xpb[(size_t)(tt + 1) * 1024 + r1];
    }
    const uint4* hq = (const uint4*)hbuf[tt & 1];
#pragma unroll
    for (int kc = 0; kc < 24; ++kc) {
      uint4 hv = hq[kc];
      a0 = fdot2u(w0[kc].x, hv.x, a0); a0 = fdot2u(w0[kc].y, hv.y, a0);
      a0 = fdot2u(w0[kc].z, hv.z, a0); a0 = fdot2u(w0[kc].w, hv.w, a0);
      a1 = fdot2u(w1[kc].x, hv.x, a1); a1 = fdot2u(w1[kc].y, hv.y, a1);
      a1 = fdot2u(w1[kc].z, hv.z, a1); a1 = fdot2u(w1[kc].w, hv.w, a1);
    }
#pragma unroll
    for (int q = 0; q < 8; ++q) {
      uint4 hv = hq[24 + q];
      uint4 t0v = *(const uint4*)(wt + (size_t)(q * 1024 + r0) * 8);
      uint4 t1v = *(const uint4*)(wt + (size_t)(q * 1024 + r1) * 8);
      a0 = fdot2u(t0v.x, hv.x, a0); a0 = fdot2u(t0v.y, hv.y, a0);
      a0 = fdot2u(t0v.z, hv.z, a0); a0 = fdot2u(t0v.w, hv.w, a0);
      a1 = fdot2u(t1v.x, hv.x, a1); a1 = fdot2u(t1v.y, hv.y, a1);
      a1 = fdot2u(t1v.z, hv.z, a1); a1 = fdot2u(t1v.w, hv.w, a1);
    }
    // exchange between lane pair (L, L^32): L<32 has (i,g), L>=32 has (f,o)
    float b0 = __shfl_xor(a0, 32);
    float b1 = __shfl_xor(a1, 32);
    float ipre = g0 ? b0 : a0;
    float fpre = g0 ? a0 : b0;
    float gpre = g0 ? b1 : a1;
    float opre = g0 ? a1 : b1;
    float iv = sig_(ipre), fv = sig_(fpre), gv = tanh_(gpre), ov = sig_(opre);
    cc = fv * cc + iv * gv;
    float hval = ov * tanh_(cc);
    hb = __builtin_bit_cast(u16, (f16)hval);
    if (g0 == 0) {
      ((u16*)hbuf[(tt + 1) & 1])[u] = hb;
      houtb[(size_t)tt * 256 + u] = hb;
    }
    __syncthreads();
  }
  if (g0 == 0) {
    cst[(size_t)b * 256 + u] = cc;
    hst[(size_t)b * 256 + u] = hb;
  }
}

// ---------------- host ----------------

extern "C" void kernel_launch(void* const* d_in, const int* in_sizes, int n_in,
                              void* d_out, int out_size, void* d_ws, size_t ws_size,
                              hipStream_t stream)
{
  const float* x      = (const float*)d_in[0];
  const float* Wih[4] = {(const float*)d_in[1], (const float*)d_in[5],
                         (const float*)d_in[9], (const float*)d_in[13]};
  const float* Whh[4] = {(const float*)d_in[2], (const float*)d_in[6],
                         (const float*)d_in[10], (const float*)d_in[14]};
  const float* bi[4]  = {(const float*)d_in[3], (const float*)d_in[7],
                         (const float*)d_in[11], (const float*)d_in[15]};
  const float* bh[4]  = {(const float*)d_in[4], (const float*)d_in[8],
                         (const float*)d_in[12], (const float*)d_in[16]};
  const float* outW   = (const float*)d_in[17];
  const float* outb   = (const float*)d_in[18];

  char* ws = (char*)d_ws;
  size_t off = 0;
  auto alc = [&](size_t bytes) -> char* {
    char* p = ws + off;
    off = (off + bytes + 255) & ~(size_t)255;
    return p;
  };

  u16* xf  = (u16*)alc((size_t)BT_ * I_ * 2);
  u16* hb0 = (u16*)alc((size_t)BT_ * H_ * 2);
  u16* hb1 = (u16*)alc((size_t)BT_ * H_ * 2);
  int wihn[4] = {G_ * I_, G_ * H_, G_ * H_, G_ * H_};
  u16 *wihH[4], *wihL[4], *whhH[4];
  float* bsum[4];
  for (int l = 0; l < 4; l++) {
    wihH[l] = (u16*)alc((size_t)wihn[l] * 2);
    wihL[l] = (u16*)alc((size_t)wihn[l] * 2);
    whhH[l] = (u16*)alc((size_t)G_ * H_ * 2);
    bsum[l] = (float*)alc((size_t)G_ * 4);
  }
  u16* owH = (u16*)alc((size_t)I_ * H_ * 2);
  u16* owL = (u16*)alc((size_t)I_ * H_ * 2);
  float* cst = (float*)alc((size_t)B_ * H_ * 4);
  u16*   hst = (u16*)alc((size_t)B_ * H_ * 2);

  int Tc = T_;
  while (Tc > 16 && off + (size_t)B_ * Tc * G_ * 4 + 4096 > ws_size) Tc >>= 1;
  float* xpb = (float*)alc((size_t)B_ * Tc * G_ * 4);
  int tcl = 0;
  while ((1 << tcl) < Tc) tcl++;

  {
    int n = BT_ * I_;
    cvt_f16<<<dim3((n + 255) / 256), dim3(256), 0, stream>>>(x, xf, n);
  }
  for (int l = 0; l < 4; l++) {
    split_w<<<dim3((wihn[l] + 255) / 256), dim3(256), 0, stream>>>(Wih[l], wihH[l], wihL[l], wihn[l]);
    cvt_f16<<<dim3((G_ * H_ + 255) / 256), dim3(256), 0, stream>>>(Whh[l], whhH[l], G_ * H_);
    bias_sum<<<dim3(4), dim3(256), 0, stream>>>(bi[l], bh[l], bsum[l], G_);
  }
  split_w<<<dim3((I_ * H_ + 255) / 256), dim3(256), 0, stream>>>(outW, owH, owL, I_ * H_);

  for (int l = 0; l < 4; l++) {
    const u16* Ain = (l == 0) ? xf : ((l == 1) ? hb0 : (l == 2) ? hb1 : hb0);
    u16* Hout = (l & 1) ? hb1 : hb0;
    int K = (l == 0) ? I_ : H_;
    for (int t0 = 0; t0 < T_; t0 += Tc) {
      gemm_ws<128><<<dim3((B_ * Tc) / 128, G_ / 128), dim3(256), 0, stream>>>(
          Ain, wihH[l], wihL[l], bsum[l], xpb, K, tcl, t0, G_);
      lstm_scan<<<dim3(B_), dim3(512), 0, stream>>>(whhH[l], xpb, Hout, cst, hst, Tc, t0);
    }
  }

  gemm_ws<64><<<dim3(BT_ / 128, 1), dim3(256), 0, stream>>>(
      hb1, owH, owL, outb, (float*)d_out, H_, 9, 0, I_);
}